// Round 11
// baseline (720.297 us; speedup 1.0000x reference)
//
#include <hip/hip_runtime.h>

#define L_ 2
#define T_ 512
#define B_ 128
#define F_ 4
#define H_ 256
#define QSIGN_MASK 0x5390
#define LOG2E  1.4426950408889634f
#define LOG2E2 2.8853900817779268f

typedef __attribute__((ext_vector_type(8))) short short8;
typedef __attribute__((ext_vector_type(4))) float f32x4;

// Mailbox: layer-0 normalized output, bf16x4 packed per (t,b); norm-1 => nonzero.
__device__ unsigned long long g_inter_q[T_][B_];

__global__ void zero_inter() {
  ((unsigned long long*)g_inter_q)[blockIdx.x * 256 + threadIdx.x] = 0ull;
}

__device__ __forceinline__ unsigned f2bf(float f) {
  unsigned u = __float_as_uint(f);
  return (u + 0x7fff + ((u >> 16) & 1)) >> 16;
}
// Weights pre-scaled by log2e (sigmoid gates) / 2*log2e (c-gate): MFMA output y
// is already in the exp2 domain. sigma = rcp(1+2^-y); tanh = fma(2,rcp(1+2^-y),-1).
__device__ __forceinline__ float sig2(float y) {
  return __builtin_amdgcn_rcpf(1.f + __builtin_amdgcn_exp2f(-y));
}
__device__ __forceinline__ float tanh2(float y) {   // y = 2*log2e*z -> tanh(z)
  return fmaf(2.f, __builtin_amdgcn_rcpf(1.f + __builtin_amdgcn_exp2f(-y)), -1.f);
}
// RNE pack, identical rounding to f2bf, 2 instrs.
__device__ __forceinline__ unsigned long long pack4bf(float a, float b, float c, float d) {
  unsigned lo, hi;
  asm("v_cvt_pk_bf16_f32 %0, %1, %2" : "=v"(lo) : "v"(a), "v"(b));
  asm("v_cvt_pk_bf16_f32 %0, %1, %2" : "=v"(hi) : "v"(c), "v"(d));
  return ((unsigned long long)hi << 32) | lo;
}

union FragU { short8 v; uint4 u; unsigned w[4]; };

// Helper-wave barrier: drains LDS only; the helper's global ops (x loads,
// mailbox publish stores) stay in flight across it. Used ONLY by the helper
// wave — compute waves keep __syncthreads (they have no outstanding vmem at
// the barrier, so semantics are identical for them). Mailbox is
// payload-as-flag relaxed agent-scope (consumer spins), so no drain needed.
#define HBAR() do { \
  asm volatile("s_waitcnt lgkmcnt(0)" ::: "memory"); \
  __builtin_amdgcn_s_barrier(); \
  asm volatile("" ::: "memory"); \
} while (0)

// Grid = 64 WGs x 320 threads (5 waves). blockIdx<32: layer-0 producer; else layer-1.
// R11 = R8's compute path BYTE-IDENTICAL (462us prof verified; single-copy h,
// in-loop sign XORs — dual +/-h copy is 3-for-3 implicated in regressions and
// is permanently discarded) + isolated helper-side deltas:
//   HBAR (no vmcnt drain on publishes), publish every step, stage-load issued
//   at TOP of the step so its latency hides under the 8 proj MFMAs.
// Compute waves 0-3: wave w owns cols u in [16w,16w+16). MFMA M rows = b*4+q;
// x-MFMA at step head seeding accumulators (C-operand carries bias); in-lane
// exp2-domain gates; one barrier/step. Helper wave 4: projection via MFMA,
// norm via rsq, mailbox publish; x/mailbox prefetch depth 2 into ring-4 sh_x.
__launch_bounds__(320, 1)
__global__ void qlstm_fused(const float* __restrict__ x_in,
                            const float* __restrict__ uhr, const float* __restrict__ uhi,
                            const float* __restrict__ uhj, const float* __restrict__ uhk,
                            const float* __restrict__ wxr, const float* __restrict__ wxi,
                            const float* __restrict__ wxj, const float* __restrict__ wxk,
                            const float* __restrict__ wxb_all,
                            const float* __restrict__ fcw_all, const float* __restrict__ fcb_all,
                            float* __restrict__ out_final)
{
  __shared__ __align__(16) unsigned short sh_h[2][4][272];  // double-buffered h (bf16)
  __shared__ unsigned long long sh_x[4][4];                 // ring-4 x, bf16x4 packed

  const int t     = threadIdx.x;
  const int role  = blockIdx.x >> 5;
  const int bg    = blockIdx.x & 31;
  const int bg0   = bg * 4;
  const int layer = role;
  const int wv    = t >> 6;
  const int lane  = t & 63;
  const int quad  = lane >> 4;
  const int sub   = lane & 15;

  const float* wb = wxb_all + layer * 4 * H_;
  const float* fw = fcw_all + layer * H_ * F_;
  const float* fb = fcb_all + layer * F_;

  for (int i = t; i < 2176; i += 320) ((unsigned short*)sh_h)[i] = 0;

  if (wv < 4) {
    // ================= COMPUTE WAVES (R8 verbatim) =================
    const int u  = wv * 16 + sub;   // B n-col / D col
    const int ba = sub >> 2;        // A-side row -> batch
    const int qa = sub & 3;         // A-side row -> q

    // persistent B fragments [g][ks], scaled into the exp2 domain per gate
    FragU Bf[32];
    FragU Bx[4];
    f32x4 bvv[4];
    {
      const float* Cc[4] = {uhr, uhi, uhj, uhk};
      const float* Xc[4] = {wxr, wxi, wxj, wxk};
      #pragma unroll
      for (int g = 0; g < 4; ++g) {
        const float kg = (g == 3) ? LOG2E2 : LOG2E;
        #pragma unroll
        for (int ks = 0; ks < 8; ++ks) {
          const int d  = ks >> 1;
          const int pp = (ks & 1) * 32 + quad * 8;
          const float* src = Cc[d] + (size_t)((layer * 4 + g) * 64 + pp) * 64 + u;
          FragU f;
          #pragma unroll
          for (int j = 0; j < 8; ++j) f.v[j] = (short)f2bf(src[j * 64] * kg);
          Bf[g * 8 + ks] = f;
        }
        FragU fx; fx.w[0] = 0; fx.w[1] = 0; fx.w[2] = 0; fx.w[3] = 0;
        if (quad == 0) {
          unsigned e0 = f2bf(Xc[0][(layer * 4 + g) * 64 + u] * kg);
          unsigned e1 = f2bf(Xc[1][(layer * 4 + g) * 64 + u] * kg);
          unsigned e2 = f2bf(Xc[2][(layer * 4 + g) * 64 + u] * kg);
          unsigned e3 = f2bf(Xc[3][(layer * 4 + g) * 64 + u] * kg);
          fx.w[0] = e0 | (e1 << 16);
          fx.w[1] = e2 | (e3 << 16);
        }
        Bx[g] = fx;
        f32x4 bv;
        #pragma unroll
        for (int r = 0; r < 4; ++r) bv[r] = wb[g * 256 + r * 64 + u] * kg;
        bvv[g] = bv;
      }
    }
    // sign masks (a = qa^d) and A-read byte offsets
    unsigned smask[4], smx[4];
    int xsh[4], aoff[8];
    #pragma unroll
    for (int d = 0; d < 4; ++d) {
      const int a = qa ^ d;
      const bool neg = (QSIGN_MASK >> (a * 4 + qa)) & 1;
      smask[d] = neg ? 0x80008000u : 0u;
      smx[d]   = neg ? 0x8000u : 0u;
      xsh[d]   = 16 * a;
    }
    #pragma unroll
    for (int ks = 0; ks < 8; ++ks)
      aoff[ks] = ba * 544 + (((qa ^ (ks >> 1)) * 64 + (ks & 1) * 32 + quad * 8) << 1);
    float cs[4] = {0.f, 0.f, 0.f, 0.f};
    __syncthreads();

    const char* hbB = (const char*)sh_h;
    for (int s = 0; s <= T_; ++s) {
      if (s < T_) {
        const char* hp = hbB + ((s + 1) & 1) * 2176;   // h[s-1]
        // x A-frag: k=d (0..3), value = sign(a,q)*x[b][a], a=q^d
        unsigned long long xq = sh_x[s & 3][ba];
        FragU Ax; Ax.w[0] = 0; Ax.w[1] = 0; Ax.w[2] = 0; Ax.w[3] = 0;
        if (quad == 0) {
          unsigned e0 = ((unsigned)(xq >> xsh[0]) & 0xffffu) ^ smx[0];
          unsigned e1 = ((unsigned)(xq >> xsh[1]) & 0xffffu) ^ smx[1];
          unsigned e2 = ((unsigned)(xq >> xsh[2]) & 0xffffu) ^ smx[2];
          unsigned e3 = ((unsigned)(xq >> xsh[3]) & 0xffffu) ^ smx[3];
          Ax.w[0] = e0 | (e1 << 16);
          Ax.w[1] = e2 | (e3 << 16);
        }
        // bias enters as the MFMA C-operand (no acc-init movs)
        f32x4 acc0 = __builtin_amdgcn_mfma_f32_16x16x32_bf16(Ax.v, Bx[0].v, bvv[0], 0, 0, 0);
        f32x4 acc1 = __builtin_amdgcn_mfma_f32_16x16x32_bf16(Ax.v, Bx[1].v, bvv[1], 0, 0, 0);
        f32x4 acc2 = __builtin_amdgcn_mfma_f32_16x16x32_bf16(Ax.v, Bx[2].v, bvv[2], 0, 0, 0);
        f32x4 acc3 = __builtin_amdgcn_mfma_f32_16x16x32_bf16(Ax.v, Bx[3].v, bvv[3], 0, 0, 0);
        #pragma unroll
        for (int ks = 0; ks < 8; ++ks) {
          FragU A;
          A.u = *(const uint4*)(hp + aoff[ks]);
          const unsigned m = smask[ks >> 1];
          A.w[0] ^= m; A.w[1] ^= m; A.w[2] ^= m; A.w[3] ^= m;
          acc0 = __builtin_amdgcn_mfma_f32_16x16x32_bf16(A.v, Bf[0 * 8 + ks].v, acc0, 0, 0, 0);
          acc1 = __builtin_amdgcn_mfma_f32_16x16x32_bf16(A.v, Bf[1 * 8 + ks].v, acc1, 0, 0, 0);
          acc2 = __builtin_amdgcn_mfma_f32_16x16x32_bf16(A.v, Bf[2 * 8 + ks].v, acc2, 0, 0, 0);
          acc3 = __builtin_amdgcn_mfma_f32_16x16x32_bf16(A.v, Bf[3 * 8 + ks].v, acc3, 0, 0, 0);
        }
        // fully in-lane gates (exp2 domain): b=quad, c = r*64+u for r=0..3
        float hv0, hv1, hv2, hv3;
        {
          float fg, ig, og, cv;
          fg = sig2(acc0[0]); ig = sig2(acc1[0]); og = sig2(acc2[0]); cv = tanh2(acc3[0]);
          cs[0] = ig * cv + fg * cs[0]; hv0 = og * tanh2(cs[0] * LOG2E2);
          fg = sig2(acc0[1]); ig = sig2(acc1[1]); og = sig2(acc2[1]); cv = tanh2(acc3[1]);
          cs[1] = ig * cv + fg * cs[1]; hv1 = og * tanh2(cs[1] * LOG2E2);
          fg = sig2(acc0[2]); ig = sig2(acc1[2]); og = sig2(acc2[2]); cv = tanh2(acc3[2]);
          cs[2] = ig * cv + fg * cs[2]; hv2 = og * tanh2(cs[2] * LOG2E2);
          fg = sig2(acc0[3]); ig = sig2(acc1[3]); og = sig2(acc2[3]); cv = tanh2(acc3[3]);
          cs[3] = ig * cv + fg * cs[3]; hv3 = og * tanh2(cs[3] * LOG2E2);
        }
        unsigned w01, w23;
        asm("v_cvt_pk_bf16_f32 %0, %1, %2" : "=v"(w01) : "v"(hv0), "v"(hv1));
        asm("v_cvt_pk_bf16_f32 %0, %1, %2" : "=v"(w23) : "v"(hv2), "v"(hv3));
        char* hw = (char*)sh_h + (s & 1) * 2176 + quad * 544;
        const int ub = u << 1;
        *(unsigned short*)(hw + ub)       = (unsigned short)w01;
        *(unsigned short*)(hw + 128 + ub) = (unsigned short)(w01 >> 16);
        *(unsigned short*)(hw + 256 + ub) = (unsigned short)w23;
        *(unsigned short*)(hw + 384 + ub) = (unsigned short)(w23 >> 16);
      }
      __syncthreads();
    }
  } else {
    // ================= HELPER WAVE (HBAR + pipelined staging) =================
    // fw^T A-frags: A[m=f][k] = fw[k][f], rows 4-15 zero
    FragU Af[8];
    #pragma unroll
    for (int ks = 0; ks < 8; ++ks) {
      FragU f;
      #pragma unroll
      for (int j = 0; j < 8; ++j) {
        const int k = ks * 32 + quad * 8 + j;
        f.v[j] = (sub < 4) ? (short)f2bf(fw[k * 4 + sub]) : (short)0;
      }
      Af[ks] = f;
    }
    const float fb0 = fb[0], fb1 = fb[1], fb2 = fb[2], fb3 = fb[3];
    const int bl = sub & 3;   // B-side col (batch), clamped for lanes >= 4

    // prologue: x slots 0,1
    if (lane < 4) {
      #pragma unroll
      for (int s0 = 0; s0 < 2; ++s0) {
        if (role == 0) {
          float4 xv = *(const float4*)(x_in + (size_t)((bg0 + lane) * T_ + s0) * F_);
          sh_x[s0][lane] = pack4bf(xv.x, xv.y, xv.z, xv.w);
        } else {
          unsigned long long v;
          while ((v = __hip_atomic_load(&g_inter_q[s0][bg0 + lane], __ATOMIC_RELAXED,
                                        __HIP_MEMORY_SCOPE_AGENT)) == 0ull)
            __builtin_amdgcn_s_sleep(1);
          sh_x[s0][lane] = v;
        }
      }
    }
    HBAR();

    for (int s = 0; s <= T_; ++s) {
      // issue stage-load for slot s+2 FIRST: latency hides under the proj MFMAs
      const bool stg = (lane < 4) && (s + 2 < T_);
      float4 xv = make_float4(0.f, 0.f, 0.f, 0.f);
      unsigned long long mv = 0ull;
      if (stg) {
        if (role == 0)
          xv = *(const float4*)(x_in + (size_t)((bg0 + lane) * T_ + s + 2) * F_);
        else
          mv = __hip_atomic_load(&g_inter_q[s + 2][bg0 + lane], __ATOMIC_RELAXED,
                                 __HIP_MEMORY_SCOPE_AGENT);
      }
      const bool doproj = (s >= 1) && (role == 0 || s == T_);
      if (doproj) {
        const char* hp = (const char*)sh_h + ((s + 1) & 1) * 2176;  // h[s-1]
        f32x4 pa = {fb0, fb1, fb2, fb3};
        #pragma unroll
        for (int ks = 0; ks < 8; ++ks) {
          FragU Bh;
          Bh.u = *(const uint4*)(hp + bl * 544 + ((ks * 32 + quad * 8) << 1));
          pa = __builtin_amdgcn_mfma_f32_16x16x32_bf16(Af[ks].v, Bh.v, pa, 0, 0, 0);
        }
        if (lane < 4) {   // quad==0, sub<4: all 4 components in-reg, batch = lane
          float p0 = pa[0], p1 = pa[1], p2 = pa[2], p3 = pa[3];
          float inv = __builtin_amdgcn_rsqf(
              fmaxf(p0*p0 + p1*p1 + p2*p2 + p3*p3, 1e-24f));
          p0 *= inv; p1 *= inv; p2 *= inv; p3 *= inv;
          if (role == 0) {
            // publish entry s-1 every step; store ack never drained (HBAR)
            __hip_atomic_store(&g_inter_q[s - 1][bg0 + lane], pack4bf(p0, p1, p2, p3),
                               __ATOMIC_RELAXED, __HIP_MEMORY_SCOPE_AGENT);
          } else {                     // consumer, s == T: final output
            *(float4*)(out_final + (bg0 + lane) * F_) = make_float4(p0, p1, p2, p3);
          }
        }
      }
      // consume the staged value
      if (stg) {
        const int slot = (s + 2) & 3;
        if (role == 0) {
          sh_x[slot][lane] = pack4bf(xv.x, xv.y, xv.z, xv.w);
        } else {
          while (mv == 0ull) {
            __builtin_amdgcn_s_sleep(1);
            mv = __hip_atomic_load(&g_inter_q[s + 2][bg0 + lane], __ATOMIC_RELAXED,
                                   __HIP_MEMORY_SCOPE_AGENT);
          }
          sh_x[slot][lane] = mv;
        }
      }
      HBAR();
    }
  }
}

extern "C" void kernel_launch(void* const* d_in, const int* in_sizes, int n_in,
                              void* d_out, int out_size, void* d_ws, size_t ws_size,
                              hipStream_t stream) {
  const float* x   = (const float*)d_in[0];
  const float* wxr = (const float*)d_in[1];
  const float* wxi = (const float*)d_in[2];
  const float* wxj = (const float*)d_in[3];
  const float* wxk = (const float*)d_in[4];
  const float* wxb = (const float*)d_in[5];
  const float* uhr = (const float*)d_in[6];
  const float* uhi = (const float*)d_in[7];
  const float* uhj = (const float*)d_in[8];
  const float* uhk = (const float*)d_in[9];
  const float* fcw = (const float*)d_in[10];
  const float* fcb = (const float*)d_in[11];
  float* out = (float*)d_out;

  zero_inter<<<dim3(T_ * B_ / 256), dim3(256), 0, stream>>>();
  qlstm_fused<<<dim3(64), dim3(320), 0, stream>>>(
      x, uhr, uhi, uhj, uhk, wxr, wxi, wxj, wxk, wxb, fcw, fcb, out);
}

// Round 12
// 596.929 us; speedup vs baseline: 1.2067x; 1.2067x over previous
//
#include <hip/hip_runtime.h>

#define L_ 2
#define T_ 512
#define B_ 128
#define F_ 4
#define H_ 256
#define QSIGN_MASK 0x5390
#define LOG2E  1.4426950408889634f
#define LOG2E2 2.8853900817779268f

typedef __attribute__((ext_vector_type(8))) short short8;
typedef __attribute__((ext_vector_type(4))) float f32x4;

// Mailbox: layer-0 normalized output, bf16x4 packed per (t,b); norm-1 => nonzero.
__device__ unsigned long long g_inter_q[T_][B_];

__global__ void zero_inter() {
  ((unsigned long long*)g_inter_q)[blockIdx.x * 256 + threadIdx.x] = 0ull;
}

__device__ __forceinline__ unsigned f2bf(float f) {
  unsigned u = __float_as_uint(f);
  return (u + 0x7fff + ((u >> 16) & 1)) >> 16;
}
// Weights pre-scaled by log2e (sigmoid gates) / 2*log2e (c-gate): MFMA output y
// is already in the exp2 domain. sigma = rcp(1+2^-y); tanh = fma(2,rcp(1+2^-y),-1).
__device__ __forceinline__ float sig2(float y) {
  return __builtin_amdgcn_rcpf(1.f + __builtin_amdgcn_exp2f(-y));
}
__device__ __forceinline__ float tanh2(float y) {   // y = 2*log2e*z -> tanh(z)
  return fmaf(2.f, __builtin_amdgcn_rcpf(1.f + __builtin_amdgcn_exp2f(-y)), -1.f);
}
// RNE pack, identical rounding to f2bf, 2 instrs.
__device__ __forceinline__ unsigned long long pack4bf(float a, float b, float c, float d) {
  unsigned lo, hi;
  asm("v_cvt_pk_bf16_f32 %0, %1, %2" : "=v"(lo) : "v"(a), "v"(b));
  asm("v_cvt_pk_bf16_f32 %0, %1, %2" : "=v"(hi) : "v"(c), "v"(d));
  return ((unsigned long long)hi << 32) | lo;
}

union FragU { short8 v; uint4 u; unsigned w[4]; };

// Grid = 64 WGs x 320 threads (5 waves). blockIdx<32: layer-0 producer; else layer-1.
// R12 = R8 (462us prof, session best) + ONE delta: early Ax build.
//   sh_x slot (s+1)&3 is written by the helper during step s-1, so it is
//   visible throughout step s. The ds_read + word-build for step s+1's x
//   A-fragment runs in step s's gate/trans tail (hidden under ~150cy of
//   trans-pipe work) and only ~4 VGPRs cross the barrier. This removes the
//   ~120cy exposed LDS lead-in that previously headed every step.
//   (R7's version of this failed via 16-reg spill + tail MFMAs — both absent.)
// Helper wave: R8 VERBATIM (publish-pairs halves store drains; __syncthreads
// vmcnt drain each step — R11 proved the in-order vmcnt FIFO makes "clever"
// non-draining variants chain load-consumes behind store-acks: +190us).
__launch_bounds__(320, 1)
__global__ void qlstm_fused(const float* __restrict__ x_in,
                            const float* __restrict__ uhr, const float* __restrict__ uhi,
                            const float* __restrict__ uhj, const float* __restrict__ uhk,
                            const float* __restrict__ wxr, const float* __restrict__ wxi,
                            const float* __restrict__ wxj, const float* __restrict__ wxk,
                            const float* __restrict__ wxb_all,
                            const float* __restrict__ fcw_all, const float* __restrict__ fcb_all,
                            float* __restrict__ out_final)
{
  __shared__ __align__(16) unsigned short sh_h[2][4][272];  // double-buffered h (bf16)
  __shared__ unsigned long long sh_x[4][4];                 // ring-4 x, bf16x4 packed

  const int t     = threadIdx.x;
  const int role  = blockIdx.x >> 5;
  const int bg    = blockIdx.x & 31;
  const int bg0   = bg * 4;
  const int layer = role;
  const int wv    = t >> 6;
  const int lane  = t & 63;
  const int quad  = lane >> 4;
  const int sub   = lane & 15;

  const float* wb = wxb_all + layer * 4 * H_;
  const float* fw = fcw_all + layer * H_ * F_;
  const float* fb = fcb_all + layer * F_;

  for (int i = t; i < 2176; i += 320) ((unsigned short*)sh_h)[i] = 0;

  if (wv < 4) {
    // ================= COMPUTE WAVES =================
    const int u  = wv * 16 + sub;   // B n-col / D col
    const int ba = sub >> 2;        // A-side row -> batch
    const int qa = sub & 3;         // A-side row -> q

    // persistent B fragments [g][ks], scaled into the exp2 domain per gate
    FragU Bf[32];
    FragU Bx[4];
    f32x4 bvv[4];
    {
      const float* Cc[4] = {uhr, uhi, uhj, uhk};
      const float* Xc[4] = {wxr, wxi, wxj, wxk};
      #pragma unroll
      for (int g = 0; g < 4; ++g) {
        const float kg = (g == 3) ? LOG2E2 : LOG2E;
        #pragma unroll
        for (int ks = 0; ks < 8; ++ks) {
          const int d  = ks >> 1;
          const int pp = (ks & 1) * 32 + quad * 8;
          const float* src = Cc[d] + (size_t)((layer * 4 + g) * 64 + pp) * 64 + u;
          FragU f;
          #pragma unroll
          for (int j = 0; j < 8; ++j) f.v[j] = (short)f2bf(src[j * 64] * kg);
          Bf[g * 8 + ks] = f;
        }
        FragU fx; fx.w[0] = 0; fx.w[1] = 0; fx.w[2] = 0; fx.w[3] = 0;
        if (quad == 0) {
          unsigned e0 = f2bf(Xc[0][(layer * 4 + g) * 64 + u] * kg);
          unsigned e1 = f2bf(Xc[1][(layer * 4 + g) * 64 + u] * kg);
          unsigned e2 = f2bf(Xc[2][(layer * 4 + g) * 64 + u] * kg);
          unsigned e3 = f2bf(Xc[3][(layer * 4 + g) * 64 + u] * kg);
          fx.w[0] = e0 | (e1 << 16);
          fx.w[1] = e2 | (e3 << 16);
        }
        Bx[g] = fx;
        f32x4 bv;
        #pragma unroll
        for (int r = 0; r < 4; ++r) bv[r] = wb[g * 256 + r * 64 + u] * kg;
        bvv[g] = bv;
      }
    }
    // sign masks (a = qa^d) and A-read byte offsets
    unsigned smask[4], smx[4];
    int xsh[4], aoff[8];
    #pragma unroll
    for (int d = 0; d < 4; ++d) {
      const int a = qa ^ d;
      const bool neg = (QSIGN_MASK >> (a * 4 + qa)) & 1;
      smask[d] = neg ? 0x80008000u : 0u;
      smx[d]   = neg ? 0x8000u : 0u;
      xsh[d]   = 16 * a;
    }
    #pragma unroll
    for (int ks = 0; ks < 8; ++ks)
      aoff[ks] = ba * 544 + (((qa ^ (ks >> 1)) * 64 + (ks & 1) * 32 + quad * 8) << 1);
    float cs[4] = {0.f, 0.f, 0.f, 0.f};
    __syncthreads();

    // Ax builder: reads sh_x[slot][ba], packs sign-adjusted bf16 words.
#define BUILD_AX(dst, slot) do { \
      unsigned long long xq = sh_x[slot][ba]; \
      (dst).w[0] = 0; (dst).w[1] = 0; (dst).w[2] = 0; (dst).w[3] = 0; \
      if (quad == 0) { \
        unsigned e0 = ((unsigned)(xq >> xsh[0]) & 0xffffu) ^ smx[0]; \
        unsigned e1 = ((unsigned)(xq >> xsh[1]) & 0xffffu) ^ smx[1]; \
        unsigned e2 = ((unsigned)(xq >> xsh[2]) & 0xffffu) ^ smx[2]; \
        unsigned e3 = ((unsigned)(xq >> xsh[3]) & 0xffffu) ^ smx[3]; \
        (dst).w[0] = e0 | (e1 << 16); \
        (dst).w[1] = e2 | (e3 << 16); \
      } \
    } while (0)

    FragU Axn;
    BUILD_AX(Axn, 0);   // x_0: prologue-staged, visible after the barrier above

    const char* hbB = (const char*)sh_h;
    for (int s = 0; s <= T_; ++s) {
      if (s < T_) {
        const char* hp = hbB + ((s + 1) & 1) * 2176;   // h[s-1]
        // x-MFMAs start immediately: Axn was built during step s-1's tail.
        f32x4 acc0 = __builtin_amdgcn_mfma_f32_16x16x32_bf16(Axn.v, Bx[0].v, bvv[0], 0, 0, 0);
        f32x4 acc1 = __builtin_amdgcn_mfma_f32_16x16x32_bf16(Axn.v, Bx[1].v, bvv[1], 0, 0, 0);
        f32x4 acc2 = __builtin_amdgcn_mfma_f32_16x16x32_bf16(Axn.v, Bx[2].v, bvv[2], 0, 0, 0);
        f32x4 acc3 = __builtin_amdgcn_mfma_f32_16x16x32_bf16(Axn.v, Bx[3].v, bvv[3], 0, 0, 0);
        #pragma unroll
        for (int ks = 0; ks < 8; ++ks) {
          FragU A;
          A.u = *(const uint4*)(hp + aoff[ks]);
          const unsigned m = smask[ks >> 1];
          A.w[0] ^= m; A.w[1] ^= m; A.w[2] ^= m; A.w[3] ^= m;
          acc0 = __builtin_amdgcn_mfma_f32_16x16x32_bf16(A.v, Bf[0 * 8 + ks].v, acc0, 0, 0, 0);
          acc1 = __builtin_amdgcn_mfma_f32_16x16x32_bf16(A.v, Bf[1 * 8 + ks].v, acc1, 0, 0, 0);
          acc2 = __builtin_amdgcn_mfma_f32_16x16x32_bf16(A.v, Bf[2 * 8 + ks].v, acc2, 0, 0, 0);
          acc3 = __builtin_amdgcn_mfma_f32_16x16x32_bf16(A.v, Bf[3 * 8 + ks].v, acc3, 0, 0, 0);
        }
        // fully in-lane gates (exp2 domain): b=quad, c = r*64+u for r=0..3
        float hv0, hv1, hv2, hv3;
        {
          float fg, ig, og, cv;
          fg = sig2(acc0[0]); ig = sig2(acc1[0]); og = sig2(acc2[0]); cv = tanh2(acc3[0]);
          cs[0] = ig * cv + fg * cs[0]; hv0 = og * tanh2(cs[0] * LOG2E2);
          fg = sig2(acc0[1]); ig = sig2(acc1[1]); og = sig2(acc2[1]); cv = tanh2(acc3[1]);
          cs[1] = ig * cv + fg * cs[1]; hv1 = og * tanh2(cs[1] * LOG2E2);
          fg = sig2(acc0[2]); ig = sig2(acc1[2]); og = sig2(acc2[2]); cv = tanh2(acc3[2]);
          cs[2] = ig * cv + fg * cs[2]; hv2 = og * tanh2(cs[2] * LOG2E2);
          fg = sig2(acc0[3]); ig = sig2(acc1[3]); og = sig2(acc2[3]); cv = tanh2(acc3[3]);
          cs[3] = ig * cv + fg * cs[3]; hv3 = og * tanh2(cs[3] * LOG2E2);
        }
        unsigned w01, w23;
        asm("v_cvt_pk_bf16_f32 %0, %1, %2" : "=v"(w01) : "v"(hv0), "v"(hv1));
        asm("v_cvt_pk_bf16_f32 %0, %1, %2" : "=v"(w23) : "v"(hv2), "v"(hv3));
        char* hw = (char*)sh_h + (s & 1) * 2176 + quad * 544;
        const int ub = u << 1;
        *(unsigned short*)(hw + ub)       = (unsigned short)w01;
        *(unsigned short*)(hw + 128 + ub) = (unsigned short)(w01 >> 16);
        *(unsigned short*)(hw + 256 + ub) = (unsigned short)w23;
        *(unsigned short*)(hw + 384 + ub) = (unsigned short)(w23 >> 16);
        // tail: build Ax for step s+1 (slot written by helper during step s-1,
        // visible all of step s). Hides under the gate/trans tail; ~4 regs live.
        if (s + 1 < T_) BUILD_AX(Axn, (s + 1) & 3);
      }
      __syncthreads();
    }
#undef BUILD_AX
  } else {
    // ================= HELPER WAVE (R8 verbatim) =================
    // fw^T A-frags: A[m=f][k] = fw[k][f], rows 4-15 zero
    FragU Af[8];
    #pragma unroll
    for (int ks = 0; ks < 8; ++ks) {
      FragU f;
      #pragma unroll
      for (int j = 0; j < 8; ++j) {
        const int k = ks * 32 + quad * 8 + j;
        f.v[j] = (sub < 4) ? (short)f2bf(fw[k * 4 + sub]) : (short)0;
      }
      Af[ks] = f;
    }
    const float fb0 = fb[0], fb1 = fb[1], fb2 = fb[2], fb3 = fb[3];
    const int bl = sub & 3;   // B-side col (batch), clamped for lanes >= 4

    // prologue: x slots 0,1
    if (lane < 4) {
      #pragma unroll
      for (int s0 = 0; s0 < 2; ++s0) {
        if (role == 0) {
          float4 xv = *(const float4*)(x_in + (size_t)((bg0 + lane) * T_ + s0) * F_);
          sh_x[s0][lane] = pack4bf(xv.x, xv.y, xv.z, xv.w);
        } else {
          unsigned long long v;
          while ((v = __hip_atomic_load(&g_inter_q[s0][bg0 + lane], __ATOMIC_RELAXED,
                                        __HIP_MEMORY_SCOPE_AGENT)) == 0ull)
            __builtin_amdgcn_s_sleep(1);
          sh_x[s0][lane] = v;
        }
      }
    }
    unsigned long long heldq = 0ull;
    __syncthreads();

    for (int s = 0; s <= T_; ++s) {
      const bool doproj = (s >= 1) && (role == 0 || s == T_);
      if (doproj) {
        const char* hp = (const char*)sh_h + ((s + 1) & 1) * 2176;  // h[s-1]
        f32x4 pa = {fb0, fb1, fb2, fb3};
        #pragma unroll
        for (int ks = 0; ks < 8; ++ks) {
          FragU Bh;
          Bh.u = *(const uint4*)(hp + bl * 544 + ((ks * 32 + quad * 8) << 1));
          pa = __builtin_amdgcn_mfma_f32_16x16x32_bf16(Af[ks].v, Bh.v, pa, 0, 0, 0);
        }
        if (lane < 4) {   // quad==0, sub<4: all 4 components in-reg, batch = lane
          float p0 = pa[0], p1 = pa[1], p2 = pa[2], p3 = pa[3];
          float inv = __builtin_amdgcn_rsqf(
              fmaxf(p0*p0 + p1*p1 + p2*p2 + p3*p3, 1e-24f));
          p0 *= inv; p1 *= inv; p2 *= inv; p3 *= inv;
          if (role == 0) {
            unsigned long long qw = pack4bf(p0, p1, p2, p3);
            if (s & 1) {
              heldq = qw;              // idx s-1 held one step
            } else {                   // publish pair (s-2, s-1): one drain per 2 steps
              __hip_atomic_store(&g_inter_q[s - 2][bg0 + lane], heldq,
                                 __ATOMIC_RELAXED, __HIP_MEMORY_SCOPE_AGENT);
              __hip_atomic_store(&g_inter_q[s - 1][bg0 + lane], qw,
                                 __ATOMIC_RELAXED, __HIP_MEMORY_SCOPE_AGENT);
            }
          } else {                     // consumer, s == T: final output
            *(float4*)(out_final + (bg0 + lane) * F_) = make_float4(p0, p1, p2, p3);
          }
        }
      }
      if (lane < 4 && s + 2 < T_) {
        const int slot = (s + 2) & 3;
        if (role == 0) {
          float4 xv = *(const float4*)(x_in + (size_t)((bg0 + lane) * T_ + s + 2) * F_);
          sh_x[slot][lane] = pack4bf(xv.x, xv.y, xv.z, xv.w);
        } else {
          unsigned long long v;
          while ((v = __hip_atomic_load(&g_inter_q[s + 2][bg0 + lane], __ATOMIC_RELAXED,
                                        __HIP_MEMORY_SCOPE_AGENT)) == 0ull)
            __builtin_amdgcn_s_sleep(1);
          sh_x[slot][lane] = v;
        }
      }
      __syncthreads();
    }
  }
}

extern "C" void kernel_launch(void* const* d_in, const int* in_sizes, int n_in,
                              void* d_out, int out_size, void* d_ws, size_t ws_size,
                              hipStream_t stream) {
  const float* x   = (const float*)d_in[0];
  const float* wxr = (const float*)d_in[1];
  const float* wxi = (const float*)d_in[2];
  const float* wxj = (const float*)d_in[3];
  const float* wxk = (const float*)d_in[4];
  const float* wxb = (const float*)d_in[5];
  const float* uhr = (const float*)d_in[6];
  const float* uhi = (const float*)d_in[7];
  const float* uhj = (const float*)d_in[8];
  const float* uhk = (const float*)d_in[9];
  const float* fcw = (const float*)d_in[10];
  const float* fcb = (const float*)d_in[11];
  float* out = (float*)d_out;

  zero_inter<<<dim3(T_ * B_ / 256), dim3(256), 0, stream>>>();
  qlstm_fused<<<dim3(64), dim3(320), 0, stream>>>(
      x, uhr, uhi, uhj, uhk, wxr, wxi, wxj, wxk, wxb, fcw, fcb, out);
}

// Round 13
// 523.002 us; speedup vs baseline: 1.3772x; 1.1414x over previous
//
#include <hip/hip_runtime.h>

#define L_ 2
#define T_ 512
#define B_ 128
#define F_ 4
#define H_ 256
#define QSIGN_MASK 0x5390
#define LOG2E  1.4426950408889634f
#define LOG2E2 2.8853900817779268f

typedef __attribute__((ext_vector_type(8))) short short8;
typedef __attribute__((ext_vector_type(4))) float f32x4;

// Mailbox: layer-0 normalized output, bf16x4 packed per (t,b); norm-1 => nonzero.
__device__ unsigned long long g_inter_q[T_][B_];

__global__ void zero_inter() {
  ((unsigned long long*)g_inter_q)[blockIdx.x * 256 + threadIdx.x] = 0ull;
}

__device__ __forceinline__ unsigned f2bf(float f) {
  unsigned u = __float_as_uint(f);
  return (u + 0x7fff + ((u >> 16) & 1)) >> 16;
}
// Weights pre-scaled by log2e (sigmoid gates) / 2*log2e (c-gate): MFMA output y
// is already in the exp2 domain. sigma = rcp(1+2^-y); tanh = fma(2,rcp(1+2^-y),-1).
__device__ __forceinline__ float sig2(float y) {
  return __builtin_amdgcn_rcpf(1.f + __builtin_amdgcn_exp2f(-y));
}
__device__ __forceinline__ float tanh2(float y) {   // y = 2*log2e*z -> tanh(z)
  return fmaf(2.f, __builtin_amdgcn_rcpf(1.f + __builtin_amdgcn_exp2f(-y)), -1.f);
}
// RNE pack, identical rounding to f2bf, 2 instrs.
__device__ __forceinline__ unsigned long long pack4bf(float a, float b, float c, float d) {
  unsigned lo, hi;
  asm("v_cvt_pk_bf16_f32 %0, %1, %2" : "=v"(lo) : "v"(a), "v"(b));
  asm("v_cvt_pk_bf16_f32 %0, %1, %2" : "=v"(hi) : "v"(c), "v"(d));
  return ((unsigned long long)hi << 32) | lo;
}

union FragU { short8 v; uint4 u; unsigned w[4]; };

// Grid = 64 WGs x 320 threads (5 waves). blockIdx<32: layer-0 producer; else layer-1.
// R13 = R8 (462us prof, session best) + early ds_read engineered under the
// 128-arch-VGPR wall (R12 post-mortem: at 320 threads the unified file splits
// 128 VGPR + 128 AGPR; Bf lives in AGPRs; arch file is FULL — any extra live
// VGPR across the barrier spills, +80us):
//  - hold only the RAW xq (2 VGPRs) across the barrier; ds_read issued at the
//    step TAIL where its ~120cy drains inside the barrier wait (the helper's
//    vmcnt drain makes it the straggler, so compute-tail latency is absorbed);
//  - freed 4 arch VGPRs by deleting smx[] (derived as smask>>16 at the head,
//    4 trans-shadowed v_lshrrev per step). Net register delta: -2.
// Helper wave: R8 VERBATIM (publish-pairs; __syncthreads — R11 closed this).
__launch_bounds__(320, 1)
__global__ void qlstm_fused(const float* __restrict__ x_in,
                            const float* __restrict__ uhr, const float* __restrict__ uhi,
                            const float* __restrict__ uhj, const float* __restrict__ uhk,
                            const float* __restrict__ wxr, const float* __restrict__ wxi,
                            const float* __restrict__ wxj, const float* __restrict__ wxk,
                            const float* __restrict__ wxb_all,
                            const float* __restrict__ fcw_all, const float* __restrict__ fcb_all,
                            float* __restrict__ out_final)
{
  __shared__ __align__(16) unsigned short sh_h[2][4][272];  // double-buffered h (bf16)
  __shared__ unsigned long long sh_x[4][4];                 // ring-4 x, bf16x4 packed

  const int t     = threadIdx.x;
  const int role  = blockIdx.x >> 5;
  const int bg    = blockIdx.x & 31;
  const int bg0   = bg * 4;
  const int layer = role;
  const int wv    = t >> 6;
  const int lane  = t & 63;
  const int quad  = lane >> 4;
  const int sub   = lane & 15;

  const float* wb = wxb_all + layer * 4 * H_;
  const float* fw = fcw_all + layer * H_ * F_;
  const float* fb = fcb_all + layer * F_;

  for (int i = t; i < 2176; i += 320) ((unsigned short*)sh_h)[i] = 0;

  if (wv < 4) {
    // ================= COMPUTE WAVES =================
    const int u  = wv * 16 + sub;   // B n-col / D col
    const int ba = sub >> 2;        // A-side row -> batch
    const int qa = sub & 3;         // A-side row -> q

    // persistent B fragments [g][ks], scaled into the exp2 domain per gate
    FragU Bf[32];
    FragU Bx[4];
    f32x4 bvv[4];
    {
      const float* Cc[4] = {uhr, uhi, uhj, uhk};
      const float* Xc[4] = {wxr, wxi, wxj, wxk};
      #pragma unroll
      for (int g = 0; g < 4; ++g) {
        const float kg = (g == 3) ? LOG2E2 : LOG2E;
        #pragma unroll
        for (int ks = 0; ks < 8; ++ks) {
          const int d  = ks >> 1;
          const int pp = (ks & 1) * 32 + quad * 8;
          const float* src = Cc[d] + (size_t)((layer * 4 + g) * 64 + pp) * 64 + u;
          FragU f;
          #pragma unroll
          for (int j = 0; j < 8; ++j) f.v[j] = (short)f2bf(src[j * 64] * kg);
          Bf[g * 8 + ks] = f;
        }
        FragU fx; fx.w[0] = 0; fx.w[1] = 0; fx.w[2] = 0; fx.w[3] = 0;
        if (quad == 0) {
          unsigned e0 = f2bf(Xc[0][(layer * 4 + g) * 64 + u] * kg);
          unsigned e1 = f2bf(Xc[1][(layer * 4 + g) * 64 + u] * kg);
          unsigned e2 = f2bf(Xc[2][(layer * 4 + g) * 64 + u] * kg);
          unsigned e3 = f2bf(Xc[3][(layer * 4 + g) * 64 + u] * kg);
          fx.w[0] = e0 | (e1 << 16);
          fx.w[1] = e2 | (e3 << 16);
        }
        Bx[g] = fx;
        f32x4 bv;
        #pragma unroll
        for (int r = 0; r < 4; ++r) bv[r] = wb[g * 256 + r * 64 + u] * kg;
        bvv[g] = bv;
      }
    }
    // sign masks (a = qa^d), x shifts, and A-read byte offsets
    unsigned smask[4];
    int xsh[4], aoff[8];
    #pragma unroll
    for (int d = 0; d < 4; ++d) {
      const int a = qa ^ d;
      const bool neg = (QSIGN_MASK >> (a * 4 + qa)) & 1;
      smask[d] = neg ? 0x80008000u : 0u;
      xsh[d]   = 16 * a;
    }
    #pragma unroll
    for (int ks = 0; ks < 8; ++ks)
      aoff[ks] = ba * 544 + (((qa ^ (ks >> 1)) * 64 + (ks & 1) * 32 + quad * 8) << 1);
    float cs[4] = {0.f, 0.f, 0.f, 0.f};
    __syncthreads();

    // raw x word for the CURRENT step, prefetched at the previous step's tail
    unsigned long long xqn = sh_x[0][ba];   // x_0: prologue-staged

    const char* hbB = (const char*)sh_h;
    for (int s = 0; s <= T_; ++s) {
      if (s < T_) {
        const char* hp = hbB + ((s + 1) & 1) * 2176;   // h[s-1]
        // build x A-frag from the held raw word (smx derived as smask>>16)
        FragU Ax; Ax.w[0] = 0; Ax.w[1] = 0; Ax.w[2] = 0; Ax.w[3] = 0;
        if (quad == 0) {
          unsigned e0 = ((unsigned)(xqn >> xsh[0]) & 0xffffu) ^ (smask[0] >> 16);
          unsigned e1 = ((unsigned)(xqn >> xsh[1]) & 0xffffu) ^ (smask[1] >> 16);
          unsigned e2 = ((unsigned)(xqn >> xsh[2]) & 0xffffu) ^ (smask[2] >> 16);
          unsigned e3 = ((unsigned)(xqn >> xsh[3]) & 0xffffu) ^ (smask[3] >> 16);
          Ax.w[0] = e0 | (e1 << 16);
          Ax.w[1] = e2 | (e3 << 16);
        }
        // bias enters as the MFMA C-operand (no acc-init movs)
        f32x4 acc0 = __builtin_amdgcn_mfma_f32_16x16x32_bf16(Ax.v, Bx[0].v, bvv[0], 0, 0, 0);
        f32x4 acc1 = __builtin_amdgcn_mfma_f32_16x16x32_bf16(Ax.v, Bx[1].v, bvv[1], 0, 0, 0);
        f32x4 acc2 = __builtin_amdgcn_mfma_f32_16x16x32_bf16(Ax.v, Bx[2].v, bvv[2], 0, 0, 0);
        f32x4 acc3 = __builtin_amdgcn_mfma_f32_16x16x32_bf16(Ax.v, Bx[3].v, bvv[3], 0, 0, 0);
        #pragma unroll
        for (int ks = 0; ks < 8; ++ks) {
          FragU A;
          A.u = *(const uint4*)(hp + aoff[ks]);
          const unsigned m = smask[ks >> 1];
          A.w[0] ^= m; A.w[1] ^= m; A.w[2] ^= m; A.w[3] ^= m;
          acc0 = __builtin_amdgcn_mfma_f32_16x16x32_bf16(A.v, Bf[0 * 8 + ks].v, acc0, 0, 0, 0);
          acc1 = __builtin_amdgcn_mfma_f32_16x16x32_bf16(A.v, Bf[1 * 8 + ks].v, acc1, 0, 0, 0);
          acc2 = __builtin_amdgcn_mfma_f32_16x16x32_bf16(A.v, Bf[2 * 8 + ks].v, acc2, 0, 0, 0);
          acc3 = __builtin_amdgcn_mfma_f32_16x16x32_bf16(A.v, Bf[3 * 8 + ks].v, acc3, 0, 0, 0);
        }
        // fully in-lane gates (exp2 domain): b=quad, c = r*64+u for r=0..3
        float hv0, hv1, hv2, hv3;
        {
          float fg, ig, og, cv;
          fg = sig2(acc0[0]); ig = sig2(acc1[0]); og = sig2(acc2[0]); cv = tanh2(acc3[0]);
          cs[0] = ig * cv + fg * cs[0]; hv0 = og * tanh2(cs[0] * LOG2E2);
          fg = sig2(acc0[1]); ig = sig2(acc1[1]); og = sig2(acc2[1]); cv = tanh2(acc3[1]);
          cs[1] = ig * cv + fg * cs[1]; hv1 = og * tanh2(cs[1] * LOG2E2);
          fg = sig2(acc0[2]); ig = sig2(acc1[2]); og = sig2(acc2[2]); cv = tanh2(acc3[2]);
          cs[2] = ig * cv + fg * cs[2]; hv2 = og * tanh2(cs[2] * LOG2E2);
          fg = sig2(acc0[3]); ig = sig2(acc1[3]); og = sig2(acc2[3]); cv = tanh2(acc3[3]);
          cs[3] = ig * cv + fg * cs[3]; hv3 = og * tanh2(cs[3] * LOG2E2);
        }
        unsigned w01, w23;
        asm("v_cvt_pk_bf16_f32 %0, %1, %2" : "=v"(w01) : "v"(hv0), "v"(hv1));
        asm("v_cvt_pk_bf16_f32 %0, %1, %2" : "=v"(w23) : "v"(hv2), "v"(hv3));
        char* hw = (char*)sh_h + (s & 1) * 2176 + quad * 544;
        const int ub = u << 1;
        *(unsigned short*)(hw + ub)       = (unsigned short)w01;
        *(unsigned short*)(hw + 128 + ub) = (unsigned short)(w01 >> 16);
        *(unsigned short*)(hw + 256 + ub) = (unsigned short)w23;
        *(unsigned short*)(hw + 384 + ub) = (unsigned short)(w23 >> 16);
        // tail: prefetch next step's raw x word (slot (s+1)&3 was written by
        // the helper during step s-1 -> visible). The ~120cy ds_read drains
        // inside the barrier wait (helper is the straggler), off the critical
        // path. Only 2 VGPRs live across the barrier.
        if (s + 1 < T_) xqn = sh_x[(s + 1) & 3][ba];
      }
      __syncthreads();
    }
  } else {
    // ================= HELPER WAVE (R8 verbatim) =================
    // fw^T A-frags: A[m=f][k] = fw[k][f], rows 4-15 zero
    FragU Af[8];
    #pragma unroll
    for (int ks = 0; ks < 8; ++ks) {
      FragU f;
      #pragma unroll
      for (int j = 0; j < 8; ++j) {
        const int k = ks * 32 + quad * 8 + j;
        f.v[j] = (sub < 4) ? (short)f2bf(fw[k * 4 + sub]) : (short)0;
      }
      Af[ks] = f;
    }
    const float fb0 = fb[0], fb1 = fb[1], fb2 = fb[2], fb3 = fb[3];
    const int bl = sub & 3;   // B-side col (batch), clamped for lanes >= 4

    // prologue: x slots 0,1
    if (lane < 4) {
      #pragma unroll
      for (int s0 = 0; s0 < 2; ++s0) {
        if (role == 0) {
          float4 xv = *(const float4*)(x_in + (size_t)((bg0 + lane) * T_ + s0) * F_);
          sh_x[s0][lane] = pack4bf(xv.x, xv.y, xv.z, xv.w);
        } else {
          unsigned long long v;
          while ((v = __hip_atomic_load(&g_inter_q[s0][bg0 + lane], __ATOMIC_RELAXED,
                                        __HIP_MEMORY_SCOPE_AGENT)) == 0ull)
            __builtin_amdgcn_s_sleep(1);
          sh_x[s0][lane] = v;
        }
      }
    }
    unsigned long long heldq = 0ull;
    __syncthreads();

    for (int s = 0; s <= T_; ++s) {
      const bool doproj = (s >= 1) && (role == 0 || s == T_);
      if (doproj) {
        const char* hp = (const char*)sh_h + ((s + 1) & 1) * 2176;  // h[s-1]
        f32x4 pa = {fb0, fb1, fb2, fb3};
        #pragma unroll
        for (int ks = 0; ks < 8; ++ks) {
          FragU Bh;
          Bh.u = *(const uint4*)(hp + bl * 544 + ((ks * 32 + quad * 8) << 1));
          pa = __builtin_amdgcn_mfma_f32_16x16x32_bf16(Af[ks].v, Bh.v, pa, 0, 0, 0);
        }
        if (lane < 4) {   // quad==0, sub<4: all 4 components in-reg, batch = lane
          float p0 = pa[0], p1 = pa[1], p2 = pa[2], p3 = pa[3];
          float inv = __builtin_amdgcn_rsqf(
              fmaxf(p0*p0 + p1*p1 + p2*p2 + p3*p3, 1e-24f));
          p0 *= inv; p1 *= inv; p2 *= inv; p3 *= inv;
          if (role == 0) {
            unsigned long long qw = pack4bf(p0, p1, p2, p3);
            if (s & 1) {
              heldq = qw;              // idx s-1 held one step
            } else {                   // publish pair (s-2, s-1): one drain per 2 steps
              __hip_atomic_store(&g_inter_q[s - 2][bg0 + lane], heldq,
                                 __ATOMIC_RELAXED, __HIP_MEMORY_SCOPE_AGENT);
              __hip_atomic_store(&g_inter_q[s - 1][bg0 + lane], qw,
                                 __ATOMIC_RELAXED, __HIP_MEMORY_SCOPE_AGENT);
            }
          } else {                     // consumer, s == T: final output
            *(float4*)(out_final + (bg0 + lane) * F_) = make_float4(p0, p1, p2, p3);
          }
        }
      }
      if (lane < 4 && s + 2 < T_) {
        const int slot = (s + 2) & 3;
        if (role == 0) {
          float4 xv = *(const float4*)(x_in + (size_t)((bg0 + lane) * T_ + s + 2) * F_);
          sh_x[slot][lane] = pack4bf(xv.x, xv.y, xv.z, xv.w);
        } else {
          unsigned long long v;
          while ((v = __hip_atomic_load(&g_inter_q[s + 2][bg0 + lane], __ATOMIC_RELAXED,
                                        __HIP_MEMORY_SCOPE_AGENT)) == 0ull)
            __builtin_amdgcn_s_sleep(1);
          sh_x[slot][lane] = v;
        }
      }
      __syncthreads();
    }
  }
}

extern "C" void kernel_launch(void* const* d_in, const int* in_sizes, int n_in,
                              void* d_out, int out_size, void* d_ws, size_t ws_size,
                              hipStream_t stream) {
  const float* x   = (const float*)d_in[0];
  const float* wxr = (const float*)d_in[1];
  const float* wxi = (const float*)d_in[2];
  const float* wxj = (const float*)d_in[3];
  const float* wxk = (const float*)d_in[4];
  const float* wxb = (const float*)d_in[5];
  const float* uhr = (const float*)d_in[6];
  const float* uhi = (const float*)d_in[7];
  const float* uhj = (const float*)d_in[8];
  const float* uhk = (const float*)d_in[9];
  const float* fcw = (const float*)d_in[10];
  const float* fcb = (const float*)d_in[11];
  float* out = (float*)d_out;

  zero_inter<<<dim3(T_ * B_ / 256), dim3(256), 0, stream>>>();
  qlstm_fused<<<dim3(64), dim3(320), 0, stream>>>(
      x, uhr, uhi, uhj, uhk, wxr, wxi, wxj, wxk, wxb, fcw, fcb, out);
}